// Round 1
// baseline (504.951 us; speedup 1.0000x reference)
//
#include <hip/hip_runtime.h>
#include <math.h>

#define NSUP 50000
#define NQ   50000
#define NH   32
#define NK   15
#define CIN  64
#define COUT 64
#define NG   8
#define INV_SIGMA (1.0f/0.6f)
#define GN_EPS 1e-5f
#define NEG  0.1f

#define QB   16            // queries per block
#define NBLK (NQ/QB)       // 3125

// workspace layout (floats)
#define OFF_CONV   0
#define OFF_ROWSUM ((size_t)NQ*64)            // NSUP floats
#define OFF_PS     (OFF_ROWSUM + NSUP)        // NBLK*8
#define OFF_PQ     (OFF_PS + (size_t)NBLK*8)  // NBLK*8
#define OFF_STAT   (OFF_PQ + (size_t)NBLK*8)  // 16 floats

// ---------------- kernel 0: per-row feature sums (for valid-neighbor count) ----
__global__ __launch_bounds__(256) void k_rowsum(const float* __restrict__ sf,
                                                float* __restrict__ rowsum) {
    int row  = (blockIdx.x * 256 + threadIdx.x) >> 6;
    int lane = threadIdx.x & 63;
    if (row >= NSUP) return;
    float v = sf[(size_t)row * 64 + lane];
    #pragma unroll
    for (int o = 32; o; o >>= 1) v += __shfl_down(v, o);
    if (lane == 0) rowsum[row] = v;
}

// ---------------- kernel 1: fused KPConv (conv + matmul + bias + /nbr_num) ----
__global__ __launch_bounds__(256) void k_conv(
    const float* __restrict__ sfeats, const float* __restrict__ qpts,
    const float* __restrict__ spts,   const int*   __restrict__ nidx,
    const float* __restrict__ kpts,   const float* __restrict__ wts,
    const float* __restrict__ bias,   const float* __restrict__ rowsum,
    float* __restrict__ conv_out, float* __restrict__ part_s, float* __restrict__ part_q)
{
    __shared__ __align__(16) float wl[QB * NK * CIN];   // 61440 B: weighted, then reused as partials
    __shared__ float kp[48];
    __shared__ __align__(16) float wsb[4][32][20];      // per-wave influence weights w[h][k]
    __shared__ int   nid[4][32];
    __shared__ float gps[4][8], gpq[4][8];

    const int tid  = threadIdx.x;
    const int wv   = tid >> 6;
    const int lane = tid & 63;
    if (tid < 45) kp[tid] = kpts[tid];
    __syncthreads();

    const int qbase = blockIdx.x * QB;
    const float biasr = bias[lane];

    float wacc[4][NK];
    #pragma unroll
    for (int q = 0; q < 4; q++)
        #pragma unroll
        for (int k = 0; k < NK; k++) wacc[q][k] = 0.f;
    float rc[4];

    // ---------------- phase 1: influence weights + h-contraction -------------
    #pragma unroll 1
    for (int qq = 0; qq < 4; qq++) {
        const int m = qbase + wv * 4 + qq;
        const float qx = qpts[m*3+0], qy = qpts[m*3+1], qz = qpts[m*3+2];

        bool val = false; float rs = 0.f;
        float dx = 0.f, dy = 0.f, dz = 0.f;
        if (lane < 32) {
            int id = nidx[(size_t)m * NH + lane];
            val = (id < NSUP);
            int ii = val ? id : 0;
            dx = spts[ii*3+0] - qx;
            dy = spts[ii*3+1] - qy;
            dz = spts[ii*3+2] - qz;
            rs = rowsum[ii];
            nid[wv][lane] = ii;
        }
        unsigned long long bal = __ballot(lane < 32 && val && rs > 0.f);
        int c = __popcll(bal);
        rc[qq] = 1.0f / (float)(c < 1 ? 1 : c);

        if (lane < 32) {
            #pragma unroll
            for (int k = 0; k < NK; k++) {
                float ex = dx - kp[k*3+0];
                float ey = dy - kp[k*3+1];
                float ez = dz - kp[k*3+2];
                float sq = ex*ex + ey*ey + ez*ez;
                float w  = 1.0f - sqrtf(sq) * INV_SIGMA;
                w = val ? fmaxf(w, 0.0f) : 0.0f;
                wsb[wv][lane][k] = w;
            }
        }
        __syncthreads();

        #pragma unroll 8
        for (int h = 0; h < NH; h++) {
            const int ih = nid[wv][h];
            const float f = sfeats[(size_t)ih * 64 + lane];   // coalesced 256B row
            float4 w0 = *(const float4*)&wsb[wv][h][0];
            float4 w1 = *(const float4*)&wsb[wv][h][4];
            float4 w2 = *(const float4*)&wsb[wv][h][8];
            float4 w3 = *(const float4*)&wsb[wv][h][12];      // [15..19] is pad, elem .w unused
            wacc[qq][0]  = fmaf(w0.x, f, wacc[qq][0]);
            wacc[qq][1]  = fmaf(w0.y, f, wacc[qq][1]);
            wacc[qq][2]  = fmaf(w0.z, f, wacc[qq][2]);
            wacc[qq][3]  = fmaf(w0.w, f, wacc[qq][3]);
            wacc[qq][4]  = fmaf(w1.x, f, wacc[qq][4]);
            wacc[qq][5]  = fmaf(w1.y, f, wacc[qq][5]);
            wacc[qq][6]  = fmaf(w1.z, f, wacc[qq][6]);
            wacc[qq][7]  = fmaf(w1.w, f, wacc[qq][7]);
            wacc[qq][8]  = fmaf(w2.x, f, wacc[qq][8]);
            wacc[qq][9]  = fmaf(w2.y, f, wacc[qq][9]);
            wacc[qq][10] = fmaf(w2.z, f, wacc[qq][10]);
            wacc[qq][11] = fmaf(w2.w, f, wacc[qq][11]);
            wacc[qq][12] = fmaf(w3.x, f, wacc[qq][12]);
            wacc[qq][13] = fmaf(w3.y, f, wacc[qq][13]);
            wacc[qq][14] = fmaf(w3.z, f, wacc[qq][14]);
        }
        __syncthreads();   // wsb reused next iteration
    }

    // stash weighted into LDS (layout [q][k][c])
    #pragma unroll
    for (int qq = 0; qq < 4; qq++)
        #pragma unroll
        for (int k = 0; k < NK; k++)
            wl[((wv*4 + qq) * NK + k) * 64 + lane] = wacc[qq][k];
    __syncthreads();

    // ---------------- phase 2: (15*64) x 64 matmul, k split over waves -------
    float acc[QB];
    #pragma unroll
    for (int q = 0; q < QB; q++) acc[q] = 0.f;

    for (int k = wv; k < NK; k += 4) {
        const float* Wk = wts + (size_t)k * CIN * COUT;
        #pragma unroll 4
        for (int c0 = 0; c0 < CIN; c0 += 4) {
            float4 a[QB];
            #pragma unroll
            for (int q = 0; q < QB; q++)
                a[q] = *(const float4*)&wl[(q * NK + k) * 64 + c0];
            #pragma unroll
            for (int j = 0; j < 4; j++) {
                const float wr = Wk[(size_t)(c0 + j) * 64 + lane];
                #pragma unroll
                for (int q = 0; q < QB; q++) {
                    const float av = ((const float*)&a[q])[j];
                    acc[q] = fmaf(av, wr, acc[q]);
                }
            }
        }
    }
    __syncthreads();   // all wl reads done; reuse as partial buffer

    float* pr = wl;    // [4][QB][64]
    #pragma unroll
    for (int q = 0; q < QB; q++) pr[(wv * QB + q) * 64 + lane] = acc[q];
    __syncthreads();

    // ---------------- finalize own 4 queries + groupnorm partials ------------
    float gl = 0.f, gq = 0.f;
    #pragma unroll
    for (int qq = 0; qq < 4; qq++) {
        const int q = wv * 4 + qq;
        float s = pr[(0*QB + q)*64 + lane] + pr[(1*QB + q)*64 + lane]
                + pr[(2*QB + q)*64 + lane] + pr[(3*QB + q)*64 + lane];
        float y = s * rc[qq] + biasr;
        conv_out[(size_t)(qbase + q) * 64 + lane] = y;
        gl += y;
        gq = fmaf(y, y, gq);
    }
    #pragma unroll
    for (int o = 1; o < 8; o <<= 1) {
        gl += __shfl_xor(gl, o);
        gq += __shfl_xor(gq, o);
    }
    if ((lane & 7) == 0) { gps[wv][lane >> 3] = gl; gpq[wv][lane >> 3] = gq; }
    __syncthreads();
    if (tid < 8) {
        float S = gps[0][tid] + gps[1][tid] + gps[2][tid] + gps[3][tid];
        float Q = gpq[0][tid] + gpq[1][tid] + gpq[2][tid] + gpq[3][tid];
        part_s[(size_t)blockIdx.x * 8 + tid] = S;
        part_q[(size_t)blockIdx.x * 8 + tid] = Q;
    }
}

// ---------------- kernel 2: deterministic stats reduction ---------------------
__global__ __launch_bounds__(256) void k_reduce(const float* __restrict__ part_s,
                                                const float* __restrict__ part_q,
                                                float* __restrict__ stat) {
    __shared__ double ds[32][8], dq[32][8];
    const int t = threadIdx.x;
    const int g = t & 7, chunk = t >> 3;
    const int per = (NBLK + 31) / 32;
    double s = 0.0, q = 0.0;
    int lo = chunk * per, hi = lo + per; if (hi > NBLK) hi = NBLK;
    for (int i = lo; i < hi; i++) {
        s += (double)part_s[(size_t)i * 8 + g];
        q += (double)part_q[(size_t)i * 8 + g];
    }
    ds[chunk][g] = s; dq[chunk][g] = q;
    __syncthreads();
    if (t < 8) {
        double S = 0.0, Q = 0.0;
        for (int cix = 0; cix < 32; cix++) { S += ds[cix][t]; Q += dq[cix][t]; }
        const double cnt = (double)(COUT / NG) * (double)NQ;   // 400000
        double mean = S / cnt;
        double var  = Q / cnt - mean * mean;
        stat[t]     = (float)mean;
        stat[8 + t] = (float)(1.0 / sqrt(var + (double)GN_EPS));
    }
}

// ---------------- kernel 3: normalize + affine + LeakyReLU --------------------
__global__ __launch_bounds__(256) void k_apply(const float* __restrict__ conv,
                                               const float* __restrict__ stat,
                                               const float* __restrict__ gamma,
                                               const float* __restrict__ beta,
                                               float* __restrict__ out) {
    const int n4 = NQ * COUT / 4;
    for (int idx = blockIdx.x * 256 + threadIdx.x; idx < n4; idx += gridDim.x * 256) {
        float4 v = ((const float4*)conv)[idx];
        const int c4 = idx & 15;
        const int g  = (c4 << 2) >> 3;
        const float mean = stat[g], istd = stat[8 + g];
        const float4 ga = ((const float4*)gamma)[c4];
        const float4 be = ((const float4*)beta)[c4];
        float4 r;
        r.x = (v.x - mean) * istd * ga.x + be.x; r.x = r.x >= 0.f ? r.x : NEG * r.x;
        r.y = (v.y - mean) * istd * ga.y + be.y; r.y = r.y >= 0.f ? r.y : NEG * r.y;
        r.z = (v.z - mean) * istd * ga.z + be.z; r.z = r.z >= 0.f ? r.z : NEG * r.z;
        r.w = (v.w - mean) * istd * ga.w + be.w; r.w = r.w >= 0.f ? r.w : NEG * r.w;
        ((float4*)out)[idx] = r;
    }
}

extern "C" void kernel_launch(void* const* d_in, const int* in_sizes, int n_in,
                              void* d_out, int out_size, void* d_ws, size_t ws_size,
                              hipStream_t stream) {
    const float* sfeats = (const float*)d_in[0];
    const float* qpts   = (const float*)d_in[1];
    const float* spts   = (const float*)d_in[2];
    const int*   nidx   = (const int*)  d_in[3];
    const float* kpts   = (const float*)d_in[4];
    const float* wts    = (const float*)d_in[5];
    const float* bias   = (const float*)d_in[6];
    const float* gamma  = (const float*)d_in[7];
    const float* beta   = (const float*)d_in[8];

    float* ws     = (float*)d_ws;
    float* conv   = ws + OFF_CONV;
    float* rowsum = ws + OFF_ROWSUM;
    float* ps     = ws + OFF_PS;
    float* pq     = ws + OFF_PQ;
    float* stat   = ws + OFF_STAT;
    float* out    = (float*)d_out;

    k_rowsum<<<dim3((NSUP + 3) / 4), dim3(256), 0, stream>>>(sfeats, rowsum);
    k_conv<<<dim3(NBLK), dim3(256), 0, stream>>>(sfeats, qpts, spts, nidx, kpts,
                                                 wts, bias, rowsum, conv, ps, pq);
    k_reduce<<<dim3(1), dim3(256), 0, stream>>>(ps, pq, stat);
    k_apply<<<dim3(2048), dim3(256), 0, stream>>>(conv, stat, gamma, beta, out);
}

// Round 2
// 291.390 us; speedup vs baseline: 1.7329x; 1.7329x over previous
//
#include <hip/hip_runtime.h>
#include <hip/hip_bf16.h>
#include <math.h>

#define NSUP 50000
#define NQ   50000
#define NH   32
#define NK   15
#define NG   8
#define INV_SIGMA (1.0f/0.6f)
#define GN_EPS 1e-5f
#define NEG  0.1f

#define QB   16
#define NBLK (NQ/QB)       // 3125

// workspace layout (float offsets)
#define OFF_ROWSUM 0
#define OFF_FB     50048                       // ushort[50000*64] = 1.6M float slots
#define OFF_WB     (OFF_FB + 1600000)          // ushort[61440] fragment-packed W
#define OFF_PS     (OFF_WB + 30720)
#define OFF_PQ     (OFF_PS + NBLK*8)
#define OFF_STAT   (OFF_PQ + NBLK*8)

typedef __attribute__((ext_vector_type(8))) short bf16x8;
typedef __attribute__((ext_vector_type(4))) float f32x4;

__device__ __forceinline__ short f2bf(float x) {
    __hip_bfloat16 h = __float2bfloat16(x);
    return *reinterpret_cast<short*>(&h);
}
__device__ __forceinline__ float bf2f(unsigned short u) {
    return __int_as_float(((int)u) << 16);
}

// ---------------- kernel 0: rowsum + bf16 feature conversion ------------------
__global__ __launch_bounds__(256) void k_prep(const float* __restrict__ sf,
                                              float* __restrict__ rowsum,
                                              unsigned short* __restrict__ fb) {
    int row  = (blockIdx.x * 256 + threadIdx.x) >> 6;
    int lane = threadIdx.x & 63;
    if (row >= NSUP) return;
    float v = sf[(size_t)row * 64 + lane];
    fb[(size_t)row * 64 + lane] = (unsigned short)f2bf(v);
    float s = v;
    #pragma unroll
    for (int o = 32; o; o >>= 1) s += __shfl_down(s, o);
    if (lane == 0) rowsum[row] = s;   // identical tree to round-1 (passed)
}

// ---------------- kernel 0b: pack W into B-fragment order, bf16 ---------------
// layout: [ks(30)][n(4)][lane(64)][j(8)] ; value = W[ks*32+(lane>>4)*8+j][n*16+(lane&15)]
__global__ __launch_bounds__(256) void k_wpack(const float* __restrict__ wts,
                                               unsigned short* __restrict__ wb) {
    int idx = blockIdx.x * 256 + threadIdx.x;
    if (idx >= 30 * 4 * 64 * 8) return;
    int j  = idx & 7;
    int l  = (idx >> 3) & 63;
    int n  = (idx >> 9) & 3;
    int ks = idx >> 11;
    int r  = ks * 32 + (l >> 4) * 8 + j;
    int d  = n * 16 + (l & 15);
    wb[idx] = (unsigned short)f2bf(wts[(size_t)r * 64 + d]);
}

// ---------------- kernel 1: fused KPConv --------------------------------------
__global__ __launch_bounds__(256, 4) void k_conv(
    const unsigned short* __restrict__ fb, const float* __restrict__ qpts,
    const float* __restrict__ spts,  const int*   __restrict__ nidx,
    const float* __restrict__ kpts,  const unsigned short* __restrict__ wb,
    const float* __restrict__ bias,  const float* __restrict__ rowsum,
    float* __restrict__ conv_out, float* __restrict__ part_s, float* __restrict__ part_q)
{
    // A-matrix (16 queries x 960) bf16, row stride 968 (1936B, +16B pad => <=2-way banks)
    __shared__ __align__(16) short wl16[16 * 968];
    __shared__ __align__(16) float kp4[NK][4];
    __shared__ float rcl[16];

    const int tid  = threadIdx.x;
    const int wv   = tid >> 6;
    const int lane = tid & 63;
    if (tid < NK) {
        kp4[tid][0] = kpts[tid*3+0];
        kp4[tid][1] = kpts[tid*3+1];
        kp4[tid][2] = kpts[tid*3+2];
        kp4[tid][3] = 0.f;
    }
    __syncthreads();

    const int qbase = blockIdx.x * QB;

    float wacc[4][NK];
    #pragma unroll
    for (int q = 0; q < 4; q++)
        #pragma unroll
        for (int k = 0; k < NK; k++) wacc[q][k] = 0.f;

    // ---------------- phase 1: influence + h-contraction (per-wave, no barriers)
    #pragma unroll 1
    for (int qq = 0; qq < 4; qq++) {
        const int m = qbase + wv * 4 + qq;
        const float qx = qpts[m*3+0], qy = qpts[m*3+1], qz = qpts[m*3+2];

        const int  id  = nidx[(size_t)m * NH + (lane & 31)];
        const bool val = (id < NSUP);
        const int  ii  = val ? id : 0;
        const float sx = spts[ii*3+0], sy = spts[ii*3+1], sz = spts[ii*3+2];
        const float rs = rowsum[ii];
        const float dx = sx - qx, dy = sy - qy, dz = sz - qz;

        unsigned long long bal = __ballot(val && rs > 0.f) & 0xFFFFFFFFull;
        int c = __popcll(bal); if (c < 1) c = 1;
        if (lane == 0) rcl[wv*4+qq] = 1.0f / (float)c;

        float wreg[NK];
        #pragma unroll
        for (int k = 0; k < NK; k++) {
            float4 kk = *(const float4*)kp4[k];
            float ex = dx - kk.x, ey = dy - kk.y, ez = dz - kk.z;
            float sq = fmaf(ex, ex, fmaf(ey, ey, ez * ez));
            float w  = 1.0f - sqrtf(sq) * INV_SIGMA;
            wreg[k]  = val ? fmaxf(w, 0.f) : 0.f;
        }

        #pragma unroll 8
        for (int h = 0; h < NH; h++) {
            const int   row = __builtin_amdgcn_readlane(ii, h);      // uniform -> SGPR base
            const float f   = bf2f(fb[(size_t)row * 64 + lane]);
            #pragma unroll
            for (int k = 0; k < NK; k++) {
                const float wk = __int_as_float(
                    __builtin_amdgcn_readlane(__float_as_int(wreg[k]), h));
                wacc[qq][k] = fmaf(wk, f, wacc[qq][k]);
            }
        }
    }

    // stash A-matrix (bf16) rows for this wave's 4 queries
    #pragma unroll
    for (int qq = 0; qq < 4; qq++) {
        const int rb = (wv*4 + qq) * 968;
        #pragma unroll
        for (int k = 0; k < NK; k++)
            wl16[rb + k*64 + lane] = f2bf(wacc[qq][k]);
    }
    __syncthreads();

    // ---------------- phase 2: 16x960 @ 960x64 via MFMA; wave wv owns N-tile wv
    f32x4 acc = {0.f, 0.f, 0.f, 0.f};
    const short* ap = &wl16[(lane & 15) * 968 + (lane >> 4) * 8];
    const unsigned short* bp = wb + ((size_t)(wv * 64 + lane)) * 8;
    #pragma unroll 6
    for (int ks = 0; ks < 30; ks++) {
        bf16x8 a = *(const bf16x8*)(ap + ks * 32);
        bf16x8 b = *(const bf16x8*)(bp + ks * 2048);
        acc = __builtin_amdgcn_mfma_f32_16x16x32_bf16(a, b, acc, 0, 0, 0);
    }

    // ---------------- epilogue: /nbr_num + bias, GN partials ---------------------
    const int   d  = wv * 16 + (lane & 15);
    const float bs = bias[d];
    float gl = 0.f, gq = 0.f;
    #pragma unroll
    for (int i = 0; i < 4; i++) {
        const int row = (lane >> 4) * 4 + i;           // query within block
        const float y = acc[i] * rcl[row] + bs;
        conv_out[(size_t)(qbase + row) * 64 + d] = y;
        gl += y;
        gq = fmaf(y, y, gq);
    }
    // reduce over lane bits {0,1,2,4,5}, keep bit3 (channel-group bit)
    #pragma unroll
    for (int msk = 1; msk <= 4; msk <<= 1) { gl += __shfl_xor(gl, msk); gq += __shfl_xor(gq, msk); }
    gl += __shfl_xor(gl, 16); gq += __shfl_xor(gq, 16);
    gl += __shfl_xor(gl, 32); gq += __shfl_xor(gq, 32);
    if ((lane & 55) == 0) {                            // lanes 0 and 8
        const int g = wv * 2 + (lane >> 3);
        part_s[(size_t)blockIdx.x * 8 + g] = gl;
        part_q[(size_t)blockIdx.x * 8 + g] = gq;
    }
}

// ---------------- kernel 2: deterministic stats reduction ---------------------
__global__ __launch_bounds__(1024) void k_reduce(const float* __restrict__ part_s,
                                                 const float* __restrict__ part_q,
                                                 float* __restrict__ stat) {
    __shared__ double ds[128][8], dq[128][8];
    const int t = threadIdx.x;
    const int g = t & 7, chunk = t >> 3;
    const int per = (NBLK + 127) / 128;                // 25
    double s = 0.0, q = 0.0;
    int lo = chunk * per, hi = lo + per; if (hi > NBLK) hi = NBLK;
    for (int i = lo; i < hi; i++) {
        s += (double)part_s[(size_t)i * 8 + g];
        q += (double)part_q[(size_t)i * 8 + g];
    }
    ds[chunk][g] = s; dq[chunk][g] = q;
    __syncthreads();
    if (t < 8) {
        double S = 0.0, Q = 0.0;
        for (int cix = 0; cix < 128; cix++) { S += ds[cix][t]; Q += dq[cix][t]; }
        const double cnt = (double)(64 / NG) * (double)NQ;   // 400000
        double mean = S / cnt;
        double var  = Q / cnt - mean * mean;
        stat[t]     = (float)mean;
        stat[8 + t] = (float)(1.0 / sqrt(var + (double)GN_EPS));
    }
}

// ---------------- kernel 3: normalize + affine + LeakyReLU (in-place) ---------
__global__ __launch_bounds__(256) void k_apply(float* __restrict__ out,
                                               const float* __restrict__ stat,
                                               const float* __restrict__ gamma,
                                               const float* __restrict__ beta) {
    const int n4 = NQ * 64 / 4;
    for (int idx = blockIdx.x * 256 + threadIdx.x; idx < n4; idx += gridDim.x * 256) {
        float4 v = ((const float4*)out)[idx];
        const int c4 = idx & 15;
        const int g  = c4 >> 1;
        const float mean = stat[g], istd = stat[8 + g];
        const float4 ga = ((const float4*)gamma)[c4];
        const float4 be = ((const float4*)beta)[c4];
        float4 r;
        r.x = (v.x - mean) * istd * ga.x + be.x; r.x = r.x >= 0.f ? r.x : NEG * r.x;
        r.y = (v.y - mean) * istd * ga.y + be.y; r.y = r.y >= 0.f ? r.y : NEG * r.y;
        r.z = (v.z - mean) * istd * ga.z + be.z; r.z = r.z >= 0.f ? r.z : NEG * r.z;
        r.w = (v.w - mean) * istd * ga.w + be.w; r.w = r.w >= 0.f ? r.w : NEG * r.w;
        ((float4*)out)[idx] = r;
    }
}

extern "C" void kernel_launch(void* const* d_in, const int* in_sizes, int n_in,
                              void* d_out, int out_size, void* d_ws, size_t ws_size,
                              hipStream_t stream) {
    const float* sfeats = (const float*)d_in[0];
    const float* qpts   = (const float*)d_in[1];
    const float* spts   = (const float*)d_in[2];
    const int*   nidx   = (const int*)  d_in[3];
    const float* kpts   = (const float*)d_in[4];
    const float* wts    = (const float*)d_in[5];
    const float* bias   = (const float*)d_in[6];
    const float* gamma  = (const float*)d_in[7];
    const float* beta   = (const float*)d_in[8];

    float* ws = (float*)d_ws;
    float*          rowsum = ws + OFF_ROWSUM;
    unsigned short* fb     = (unsigned short*)(ws + OFF_FB);
    unsigned short* wb     = (unsigned short*)(ws + OFF_WB);
    float*          ps     = ws + OFF_PS;
    float*          pq     = ws + OFF_PQ;
    float*          stat   = ws + OFF_STAT;
    float*          out    = (float*)d_out;

    k_prep <<<dim3((NSUP + 3) / 4), dim3(256), 0, stream>>>(sfeats, rowsum, fb);
    k_wpack<<<dim3(240),            dim3(256), 0, stream>>>(wts, wb);
    k_conv <<<dim3(NBLK),           dim3(256), 0, stream>>>(fb, qpts, spts, nidx, kpts,
                                                            wb, bias, rowsum, out, ps, pq);
    k_reduce<<<dim3(1),  dim3(1024), 0, stream>>>(ps, pq, stat);
    k_apply <<<dim3(1024), dim3(256), 0, stream>>>(out, stat, gamma, beta);
}

// Round 5
// 103.892 us; speedup vs baseline: 4.8604x; 2.8047x over previous
//
#include <hip/hip_runtime.h>
#include <hip/hip_bf16.h>
#include <math.h>

#define NSUP 50000
#define NQ   50000
#define NH   32
#define NK   15
#define NG   8
#define INV_SIGMA (1.0f/0.6f)
#define GN_EPS 1e-5f
#define NEG  0.1f

#define QB   16
#define NBLK (NQ/QB)       // 3125

// workspace layout (float offsets) — identical to R2 (verified)
#define OFF_ROWSUM 0
#define OFF_FB     50048                       // ushort[50000*64]
#define OFF_WB     (OFF_FB + 1600000)          // ushort[61440] fragment-packed W
#define OFF_PS     (OFF_WB + 30720)
#define OFF_PQ     (OFF_PS + NBLK*8)
#define OFF_STAT   (OFF_PQ + NBLK*8)

typedef __attribute__((ext_vector_type(8))) short bf16x8;
typedef __attribute__((ext_vector_type(4))) float f32x4;
typedef __attribute__((ext_vector_type(4))) unsigned int u32x4;

__device__ __forceinline__ short f2bf(float x) {
    __hip_bfloat16 h = __float2bfloat16(x);
    return *reinterpret_cast<short*>(&h);
}

// ---------------- kernel 0: rowsum + bf16 feature conversion ------------------
__global__ __launch_bounds__(256) void k_prep(const float* __restrict__ sf,
                                              float* __restrict__ rowsum,
                                              unsigned short* __restrict__ fb) {
    int row  = (blockIdx.x * 256 + threadIdx.x) >> 6;
    int lane = threadIdx.x & 63;
    if (row >= NSUP) return;
    float v = sf[(size_t)row * 64 + lane];
    fb[(size_t)row * 64 + lane] = (unsigned short)f2bf(v);
    float s = v;
    #pragma unroll
    for (int o = 32; o; o >>= 1) s += __shfl_down(s, o);
    if (lane == 0) rowsum[row] = s;
}

// ---------------- kernel 0b: pack W into B-fragment order, bf16 (R2-exact) ----
// layout: [ks(30)][n(4)][lane(64)][j(8)] ; value = W[ks*32+(l>>4)*8+j][n*16+(l&15)]
__global__ __launch_bounds__(256) void k_wpack(const float* __restrict__ wts,
                                               unsigned short* __restrict__ wb) {
    int idx = blockIdx.x * 256 + threadIdx.x;
    if (idx >= 30 * 4 * 64 * 8) return;
    int j  = idx & 7;
    int l  = (idx >> 3) & 63;
    int n  = (idx >> 9) & 3;
    int ks = idx >> 11;
    int r  = ks * 32 + ((l >> 4) << 3) + j;
    int d  = n * 16 + (l & 15);
    wb[idx] = (unsigned short)f2bf(wts[(size_t)r * 64 + d]);
}

// ---------------- kernel 1: fused KPConv, both phases MFMA --------------------
__global__ __launch_bounds__(256, 4) void k_conv(
    const unsigned short* __restrict__ fb, const float* __restrict__ qpts,
    const float* __restrict__ spts,  const int*   __restrict__ nidx,
    const float* __restrict__ kpts,  const unsigned short* __restrict__ wb,
    const float* __restrict__ bias,  const float* __restrict__ rowsum,
    float* __restrict__ conv_out, float* __restrict__ part_s, float* __restrict__ part_q)
{
    // phase-2 A matrix [16 q][968] bf16 (R2-verified layout); phase-1 aliases:
    //   per wave (6144B): [0,1024) dxyz float4[2][32]; [1024,6144) F panels
    //   4 panels x [16 c][40 h-padded] bf16 (80B row stride), 1280B each
    __shared__ __align__(16) short wl16[16 * 968];
    __shared__ __align__(16) float kp4[16][4];
    __shared__ float rcl[16];

    const int tid  = threadIdx.x;
    const int wv   = tid >> 6;
    const int lane = tid & 63;
    const int g    = lane >> 4;
    const int c16  = lane & 15;

    if (tid < 16) {
        if (tid < NK) {
            kp4[tid][0] = kpts[tid*3+0];
            kp4[tid][1] = kpts[tid*3+1];
            kp4[tid][2] = kpts[tid*3+2];
        } else {
            kp4[tid][0] = 1e8f; kp4[tid][1] = 1e8f; kp4[tid][2] = 1e8f;  // k=15 -> w=0
        }
        kp4[tid][3] = 0.f;
    }
    __syncthreads();

    const float kx = kp4[c16][0], ky = kp4[c16][1], kz = kp4[c16][2];

    const int qbase = blockIdx.x * QB;
    char* WV = (char*)wl16 + wv * 6144;
    f32x4* XY = (f32x4*)WV;            // [2][32]
    char*  FP = WV + 1024;             // 4 panels x 1280B

    f32x4 pacc[4][4];
    #pragma unroll
    for (int a = 0; a < 4; a++)
        #pragma unroll
        for (int b = 0; b < 4; b++) pacc[a][b] = (f32x4){0.f,0.f,0.f,0.f};

    const int h    = lane & 31;
    const int half = lane >> 5;

    #pragma unroll
    for (int pp = 0; pp < 2; pp++) {
        // ---- stage dxyz for queries 2pp (lanes 0-31) and 2pp+1 (lanes 32-63)
        {
            const int qq = pp*2 + half;
            const int m  = qbase + wv*4 + qq;
            const float qx = qpts[m*3+0], qy = qpts[m*3+1], qz = qpts[m*3+2];
            const int  id  = nidx[(size_t)m * NH + h];
            const bool val = (id < NSUP);
            const int  ii  = val ? id : 0;
            const float dx = spts[ii*3+0]-qx, dy = spts[ii*3+1]-qy, dz = spts[ii*3+2]-qz;
            const float rs = rowsum[ii];
            unsigned long long bal = __ballot(val && rs > 0.f);
            int cA = __popcll(bal & 0xffffffffull); if (cA < 1) cA = 1;
            int cB = __popcll(bal >> 32);           if (cB < 1) cB = 1;
            if (lane == 0)  rcl[wv*4 + pp*2]     = 1.0f / (float)cA;
            if (lane == 32) rcl[wv*4 + pp*2 + 1] = 1.0f / (float)cB;
            f32x4 st; st.x = val ? dx : 1e10f; st.y = dy; st.z = dz; st.w = 0.f;
            XY[half*32 + h] = st;      // same-wave DS: compiler orders reads below
        }

        #pragma unroll
        for (int e = 0; e < 2; e++) {
            const int q2 = pp*2 + e;
            const int m2 = qbase + wv*4 + q2;

            // ---- A-fragment in registers: w[h=8g+j][k=c16], j=0..7
            union { unsigned short u[8]; bf16x8 v; } ua;
            #pragma unroll
            for (int j = 0; j < 8; j++) {
                f32x4 p = XY[e*32 + g*8 + j];
                float ex = p.x - kx, ey = p.y - ky, ez = p.z - kz;
                float sq = fmaf(ex, ex, fmaf(ey, ey, ez * ez));
                float w  = fmaxf(1.0f - sqrtf(sq) * INV_SIGMA, 0.f);
                ua.u[j]  = (unsigned short)f2bf(w);
            }

            // ---- gather F rows, store TRANSPOSED [c][h] (80B row stride)
            #pragma unroll
            for (int i = 0; i < 4; i++) {
                const int r = i*8 + (lane >> 3);
                const int s = lane & 7;
                int id2 = nidx[(size_t)m2 * NH + r];
                id2 = (id2 < NSUP) ? id2 : 0;
                u32x4 v = *(const u32x4*)((const char*)fb + (size_t)id2*128 + s*16);
                const unsigned short* vs = (const unsigned short*)&v;
                #pragma unroll
                for (int cc = 0; cc < 8; cc++) {
                    const int c   = s*8 + cc;
                    const int pan = c >> 4;
                    const int cl  = c & 15;
                    *(unsigned short*)(FP + pan*1280 + cl*80 + r*2) = vs[cc];
                }
            }

            // ---- B-fragments (plain contiguous b128, R2-verified frag shape) + MFMA
            #pragma unroll
            for (int ct = 0; ct < 4; ct++) {
                bf16x8 b = *(const bf16x8*)(FP + ct*1280 + c16*80 + g*16);
                pacc[q2][ct] = __builtin_amdgcn_mfma_f32_16x16x32_bf16(ua.v, b, pacc[q2][ct], 0, 0, 0);
            }
        }
    }

    __syncthreads();     // phase-1 LDS dead; wl16 becomes the phase-2 A matrix

    // ---- write A matrix in R2-exact layout: p = k*64 + c, row stride 968 ----
    #pragma unroll
    for (int qq = 0; qq < 4; qq++) {
        #pragma unroll
        for (int ct = 0; ct < 4; ct++) {
            #pragma unroll
            for (int i = 0; i < 4; i++) {
                const int kk = g*4 + i;
                if (kk < NK)   // k=15 row is zero and outside the 968 stride
                    wl16[(wv*4 + qq)*968 + kk*64 + ct*16 + c16] = f2bf(pacc[qq][ct][i]);
            }
        }
    }
    __syncthreads();

    // ---------------- phase 2: 16x960 @ 960x64 via MFMA (R2-exact) -----------
    f32x4 facc = (f32x4){0.f,0.f,0.f,0.f};
    const short* ap = wl16 + (lane & 15)*968 + (lane >> 4)*8;
    const unsigned short* bp = wb + ((size_t)(wv * 64 + lane)) * 8;
    #pragma unroll 6
    for (int ks = 0; ks < 30; ks++) {
        bf16x8 a = *(const bf16x8*)(ap + ks*32);
        bf16x8 b = *(const bf16x8*)(bp + (size_t)ks*2048);
        facc = __builtin_amdgcn_mfma_f32_16x16x32_bf16(a, b, facc, 0, 0, 0);
    }

    // ---------------- epilogue: /nbr_num + bias, GN partials (R2-exact) ------
    const int   d  = wv*16 + (lane & 15);
    const float bs = bias[d];
    float gl = 0.f, gq = 0.f;
    #pragma unroll
    for (int i = 0; i < 4; i++) {
        const int row = (lane >> 4)*4 + i;
        const float y = facc[i] * rcl[row] + bs;
        conv_out[(size_t)(qbase + row)*64 + d] = y;
        gl += y;
        gq = fmaf(y, y, gq);
    }
    #pragma unroll
    for (int msk = 1; msk <= 4; msk <<= 1) { gl += __shfl_xor(gl, msk); gq += __shfl_xor(gq, msk); }
    gl += __shfl_xor(gl, 16); gq += __shfl_xor(gq, 16);
    gl += __shfl_xor(gl, 32); gq += __shfl_xor(gq, 32);
    if ((lane & 55) == 0) {
        const int grp = wv*2 + (lane >> 3);
        part_s[(size_t)blockIdx.x * 8 + grp] = gl;
        part_q[(size_t)blockIdx.x * 8 + grp] = gq;
    }
}

// ---------------- kernel 2: deterministic stats reduction ---------------------
__global__ __launch_bounds__(1024) void k_reduce(const float* __restrict__ part_s,
                                                 const float* __restrict__ part_q,
                                                 float* __restrict__ stat) {
    __shared__ double ds[128][8], dq[128][8];
    const int t = threadIdx.x;
    const int g = t & 7, chunk = t >> 3;
    const int per = (NBLK + 127) / 128;
    double s = 0.0, q = 0.0;
    int lo = chunk * per, hi = lo + per; if (hi > NBLK) hi = NBLK;
    for (int i = lo; i < hi; i++) {
        s += (double)part_s[(size_t)i * 8 + g];
        q += (double)part_q[(size_t)i * 8 + g];
    }
    ds[chunk][g] = s; dq[chunk][g] = q;
    __syncthreads();
    if (t < 8) {
        double S = 0.0, Q = 0.0;
        for (int cix = 0; cix < 128; cix++) { S += ds[cix][t]; Q += dq[cix][t]; }
        const double cnt = (double)(64 / NG) * (double)NQ;
        double mean = S / cnt;
        double var  = Q / cnt - mean * mean;
        stat[t]     = (float)mean;
        stat[8 + t] = (float)(1.0 / sqrt(var + (double)GN_EPS));
    }
}

// ---------------- kernel 3: normalize + affine + LeakyReLU (in-place) ---------
__global__ __launch_bounds__(256) void k_apply(float* __restrict__ out,
                                               const float* __restrict__ stat,
                                               const float* __restrict__ gamma,
                                               const float* __restrict__ beta) {
    const int n4 = NQ * 64 / 4;
    for (int idx = blockIdx.x * 256 + threadIdx.x; idx < n4; idx += gridDim.x * 256) {
        float4 v = ((const float4*)out)[idx];
        const int c4 = idx & 15;
        const int g  = c4 >> 1;
        const float mean = stat[g], istd = stat[8 + g];
        const float4 ga = ((const float4*)gamma)[c4];
        const float4 be = ((const float4*)beta)[c4];
        float4 r;
        r.x = (v.x - mean) * istd * ga.x + be.x; r.x = r.x >= 0.f ? r.x : NEG * r.x;
        r.y = (v.y - mean) * istd * ga.y + be.y; r.y = r.y >= 0.f ? r.y : NEG * r.y;
        r.z = (v.z - mean) * istd * ga.z + be.z; r.z = r.z >= 0.f ? r.z : NEG * r.z;
        r.w = (v.w - mean) * istd * ga.w + be.w; r.w = r.w >= 0.f ? r.w : NEG * r.w;
        ((float4*)out)[idx] = r;
    }
}

extern "C" void kernel_launch(void* const* d_in, const int* in_sizes, int n_in,
                              void* d_out, int out_size, void* d_ws, size_t ws_size,
                              hipStream_t stream) {
    const float* sfeats = (const float*)d_in[0];
    const float* qpts   = (const float*)d_in[1];
    const float* spts   = (const float*)d_in[2];
    const int*   nidx   = (const int*)  d_in[3];
    const float* kpts   = (const float*)d_in[4];
    const float* wts    = (const float*)d_in[5];
    const float* bias   = (const float*)d_in[6];
    const float* gamma  = (const float*)d_in[7];
    const float* beta   = (const float*)d_in[8];

    float* ws = (float*)d_ws;
    float*          rowsum = ws + OFF_ROWSUM;
    unsigned short* fb     = (unsigned short*)(ws + OFF_FB);
    unsigned short* wb     = (unsigned short*)(ws + OFF_WB);
    float*          ps     = ws + OFF_PS;
    float*          pq     = ws + OFF_PQ;
    float*          stat   = ws + OFF_STAT;
    float*          out    = (float*)d_out;

    k_prep <<<dim3((NSUP + 3) / 4), dim3(256), 0, stream>>>(sfeats, rowsum, fb);
    k_wpack<<<dim3(240),            dim3(256), 0, stream>>>(wts, wb);
    k_conv <<<dim3(NBLK),           dim3(256), 0, stream>>>(fb, qpts, spts, nidx, kpts,
                                                            wb, bias, rowsum, out, ps, pq);
    k_reduce<<<dim3(1),   dim3(1024), 0, stream>>>(ps, pq, stat);
    k_apply <<<dim3(1024), dim3(256), 0, stream>>>(out, stat, gamma, beta);
}

// Round 6
// 82.004 us; speedup vs baseline: 6.1576x; 1.2669x over previous
//
#include <hip/hip_runtime.h>
#include <hip/hip_bf16.h>
#include <math.h>

#define NSUP 50000
#define NQ   50000
#define NH   32
#define NK   15
#define NG   8
#define INV_SIGMA (1.0f/0.6f)
#define GN_EPS 1e-5f
#define NEG  0.1f

#define QB   16
#define NBLK (NQ/QB)       // 3125

// workspace layout (float offsets) — identical to R2 (verified)
#define OFF_ROWSUM 0
#define OFF_FB     50048                       // ushort[50000*64]
#define OFF_WB     (OFF_FB + 1600000)          // ushort[61440] fragment-packed W
#define OFF_PS     (OFF_WB + 30720)
#define OFF_PQ     (OFF_PS + NBLK*8)
#define OFF_STAT   (OFF_PQ + NBLK*8)

typedef __attribute__((ext_vector_type(8))) short bf16x8;
typedef __attribute__((ext_vector_type(4))) float f32x4;
typedef __attribute__((ext_vector_type(4))) unsigned int u32x4;

__device__ __forceinline__ short f2bf(float x) {
    __hip_bfloat16 h = __float2bfloat16(x);
    return *reinterpret_cast<short*>(&h);
}

// ---------------- kernel 0: rowsum + bf16 feature conversion ------------------
__global__ __launch_bounds__(256) void k_prep(const float* __restrict__ sf,
                                              float* __restrict__ rowsum,
                                              unsigned short* __restrict__ fb) {
    int row  = (blockIdx.x * 256 + threadIdx.x) >> 6;
    int lane = threadIdx.x & 63;
    if (row >= NSUP) return;
    float v = sf[(size_t)row * 64 + lane];
    fb[(size_t)row * 64 + lane] = (unsigned short)f2bf(v);
    float s = v;
    #pragma unroll
    for (int o = 32; o; o >>= 1) s += __shfl_down(s, o);
    if (lane == 0) rowsum[row] = s;
}

// ---------------- kernel 0b: pack W into B-fragment order, bf16 (R2-exact) ----
// layout: [ks(30)][n(4)][lane(64)][j(8)] ; value = W[ks*32+(l>>4)*8+j][n*16+(l&15)]
__global__ __launch_bounds__(256) void k_wpack(const float* __restrict__ wts,
                                               unsigned short* __restrict__ wb) {
    int idx = blockIdx.x * 256 + threadIdx.x;
    if (idx >= 30 * 4 * 64 * 8) return;
    int j  = idx & 7;
    int l  = (idx >> 3) & 63;
    int n  = (idx >> 9) & 3;
    int ks = idx >> 11;
    int r  = ks * 32 + ((l >> 4) << 3) + j;
    int d  = n * 16 + (l & 15);
    wb[idx] = (unsigned short)f2bf(wts[(size_t)r * 64 + d]);
}

// ---------------- kernel 1: fused KPConv, both phases MFMA --------------------
__global__ __launch_bounds__(256, 5) void k_conv(
    const unsigned short* __restrict__ fb, const float* __restrict__ qpts,
    const float* __restrict__ spts,  const int*   __restrict__ nidx,
    const float* __restrict__ kpts,  const unsigned short* __restrict__ wb,
    const float* __restrict__ bias,  const float* __restrict__ rowsum,
    float* __restrict__ conv_out, float* __restrict__ part_s, float* __restrict__ part_q)
{
    // phase-2 A matrix [16 q][968] bf16 (R2-verified layout); phase-1 aliases per
    // wave (6144B): [0,1024) dxyz f32x4[2][32]; [1024,5632) F tile [32 h][144B]
    // with 16B-chunk XOR swizzle: chunk' = chunk ^ ((h>>3)&3)  -> 2-way reads
    __shared__ __align__(16) short wl16[16 * 968];
    __shared__ __align__(16) float kp4[16][4];
    __shared__ float rcl[16];

    const int tid  = threadIdx.x;
    const int wv   = tid >> 6;
    const int lane = tid & 63;
    const int g    = lane >> 4;
    const int c16  = lane & 15;

    if (tid < 16) {
        if (tid < NK) {
            kp4[tid][0] = kpts[tid*3+0];
            kp4[tid][1] = kpts[tid*3+1];
            kp4[tid][2] = kpts[tid*3+2];
        } else {
            kp4[tid][0] = 1e8f; kp4[tid][1] = 1e8f; kp4[tid][2] = 1e8f;  // k=15 -> w=0
        }
        kp4[tid][3] = 0.f;
    }
    __syncthreads();

    const float kx = kp4[c16][0], ky = kp4[c16][1], kz = kp4[c16][2];

    const int qbase = blockIdx.x * QB;
    char* WV = (char*)wl16 + wv * 6144;
    f32x4* XY = (f32x4*)WV;            // [2][32] dxyz
    char*  FP = WV + 1024;             // [32 h][144B], XOR-swizzled chunks

    f32x4 pacc[4][4];
    #pragma unroll
    for (int a = 0; a < 4; a++)
        #pragma unroll
        for (int b = 0; b < 4; b++) pacc[a][b] = (f32x4){0.f,0.f,0.f,0.f};

    const int h    = lane & 31;
    const int half = lane >> 5;

    #pragma unroll
    for (int pp = 0; pp < 2; pp++) {
        // ---- stage dxyz for queries 2pp (lanes 0-31) and 2pp+1 (lanes 32-63)
        {
            const int qq = pp*2 + half;
            const int m  = qbase + wv*4 + qq;
            const float qx = qpts[m*3+0], qy = qpts[m*3+1], qz = qpts[m*3+2];
            const int  id  = nidx[(size_t)m * NH + h];
            const bool val = (id < NSUP);
            const int  ii  = val ? id : 0;
            const float dx = spts[ii*3+0]-qx, dy = spts[ii*3+1]-qy, dz = spts[ii*3+2]-qz;
            const float rs = rowsum[ii];
            unsigned long long bal = __ballot(val && rs > 0.f);
            int cA = __popcll(bal & 0xffffffffull); if (cA < 1) cA = 1;
            int cB = __popcll(bal >> 32);           if (cB < 1) cB = 1;
            if (lane == 0)  rcl[wv*4 + pp*2]     = 1.0f / (float)cA;
            if (lane == 32) rcl[wv*4 + pp*2 + 1] = 1.0f / (float)cB;
            f32x4 st; st.x = val ? dx : 1e10f; st.y = dy; st.z = dz; st.w = 0.f;
            XY[half*32 + h] = st;      // same-wave DS: compiler orders reads below
        }

        #pragma unroll
        for (int e = 0; e < 2; e++) {
            const int q2 = pp*2 + e;
            const int m2 = qbase + wv*4 + q2;

            // ---- A-fragment in registers: w[h=8g+j][k=c16], j=0..7
            union { unsigned short u[8]; bf16x8 v; } ua;
            #pragma unroll
            for (int j = 0; j < 8; j++) {
                f32x4 p = XY[e*32 + g*8 + j];
                float ex = p.x - kx, ey = p.y - ky, ez = p.z - kz;
                float sq = fmaf(ex, ex, fmaf(ey, ey, ez * ez));
                float w  = fmaxf(1.0f - sqrtf(sq) * INV_SIGMA, 0.f);
                ua.u[j]  = (unsigned short)f2bf(w);
            }

            // ---- gather F rows -> row-major [h][144B], b128 writes, XOR chunks
            #pragma unroll
            for (int i = 0; i < 4; i++) {
                const int r = i*8 + (lane >> 3);
                const int s = lane & 7;
                int id2 = nidx[(size_t)m2 * NH + r];
                id2 = (id2 < NSUP) ? id2 : 0;
                u32x4 v = *(const u32x4*)((const char*)fb + (size_t)id2*128 + s*16);
                *(u32x4*)(FP + r*144 + ((s ^ (i & 3)) << 4)) = v;
            }

            // ---- B-fragments: 8x ds_read_u16 per c-tile, 2-way banks, + MFMA
            #pragma unroll
            for (int ct = 0; ct < 4; ct++) {
                const char* vb = FP + (g*8)*144
                               + (((((ct << 1) | (c16 >> 3)) ^ g) & 7) << 4)
                               + ((c16 & 7) << 1);
                union { unsigned short u[8]; bf16x8 v; } ub;
                #pragma unroll
                for (int j = 0; j < 8; j++)
                    ub.u[j] = *(const unsigned short*)(vb + j*144);
                pacc[q2][ct] = __builtin_amdgcn_mfma_f32_16x16x32_bf16(ua.v, ub.v, pacc[q2][ct], 0, 0, 0);
            }
        }
    }

    __syncthreads();     // phase-1 LDS dead; wl16 becomes the phase-2 A matrix

    // ---- write A matrix in R2-exact layout: p = k*64 + c, row stride 968 ----
    #pragma unroll
    for (int qq = 0; qq < 4; qq++) {
        #pragma unroll
        for (int ct = 0; ct < 4; ct++) {
            #pragma unroll
            for (int i = 0; i < 4; i++) {
                const int kk = g*4 + i;
                if (kk < NK)   // k=15 row is zero and outside the 968 stride
                    wl16[(wv*4 + qq)*968 + kk*64 + ct*16 + c16] = f2bf(pacc[qq][ct][i]);
            }
        }
    }
    __syncthreads();

    // ---------------- phase 2: 16x960 @ 960x64 via MFMA (R2-exact) -----------
    f32x4 facc = (f32x4){0.f,0.f,0.f,0.f};
    const short* ap = wl16 + (lane & 15)*968 + (lane >> 4)*8;
    const unsigned short* bp = wb + ((size_t)(wv * 64 + lane)) * 8;
    #pragma unroll 6
    for (int ks = 0; ks < 30; ks++) {
        bf16x8 a = *(const bf16x8*)(ap + ks*32);
        bf16x8 b = *(const bf16x8*)(bp + (size_t)ks*2048);
        facc = __builtin_amdgcn_mfma_f32_16x16x32_bf16(a, b, facc, 0, 0, 0);
    }

    // ---------------- epilogue: /nbr_num + bias, GN partials (R2-exact) ------
    const int   d  = wv*16 + (lane & 15);
    const float bs = bias[d];
    float gl = 0.f, gq = 0.f;
    #pragma unroll
    for (int i = 0; i < 4; i++) {
        const int row = (lane >> 4)*4 + i;
        const float y = facc[i] * rcl[row] + bs;
        conv_out[(size_t)(qbase + row)*64 + d] = y;
        gl += y;
        gq = fmaf(y, y, gq);
    }
    #pragma unroll
    for (int msk = 1; msk <= 4; msk <<= 1) { gl += __shfl_xor(gl, msk); gq += __shfl_xor(gq, msk); }
    gl += __shfl_xor(gl, 16); gq += __shfl_xor(gq, 16);
    gl += __shfl_xor(gl, 32); gq += __shfl_xor(gq, 32);
    if ((lane & 55) == 0) {
        const int grp = wv*2 + (lane >> 3);
        part_s[(size_t)blockIdx.x * 8 + grp] = gl;
        part_q[(size_t)blockIdx.x * 8 + grp] = gq;
    }
}

// ---------------- kernel 2: deterministic stats reduction ---------------------
__global__ __launch_bounds__(1024) void k_reduce(const float* __restrict__ part_s,
                                                 const float* __restrict__ part_q,
                                                 float* __restrict__ stat) {
    __shared__ double ds[128][8], dq[128][8];
    const int t = threadIdx.x;
    const int g = t & 7, chunk = t >> 3;
    const int per = (NBLK + 127) / 128;
    double s = 0.0, q = 0.0;
    int lo = chunk * per, hi = lo + per; if (hi > NBLK) hi = NBLK;
    for (int i = lo; i < hi; i++) {
        s += (double)part_s[(size_t)i * 8 + g];
        q += (double)part_q[(size_t)i * 8 + g];
    }
    ds[chunk][g] = s; dq[chunk][g] = q;
    __syncthreads();
    if (t < 8) {
        double S = 0.0, Q = 0.0;
        for (int cix = 0; cix < 128; cix++) { S += ds[cix][t]; Q += dq[cix][t]; }
        const double cnt = (double)(64 / NG) * (double)NQ;
        double mean = S / cnt;
        double var  = Q / cnt - mean * mean;
        stat[t]     = (float)mean;
        stat[8 + t] = (float)(1.0 / sqrt(var + (double)GN_EPS));
    }
}

// ---------------- kernel 3: normalize + affine + LeakyReLU (in-place) ---------
__global__ __launch_bounds__(256) void k_apply(float* __restrict__ out,
                                               const float* __restrict__ stat,
                                               const float* __restrict__ gamma,
                                               const float* __restrict__ beta) {
    const int n4 = NQ * 64 / 4;
    for (int idx = blockIdx.x * 256 + threadIdx.x; idx < n4; idx += gridDim.x * 256) {
        float4 v = ((const float4*)out)[idx];
        const int c4 = idx & 15;
        const int g  = c4 >> 1;
        const float mean = stat[g], istd = stat[8 + g];
        const float4 ga = ((const float4*)gamma)[c4];
        const float4 be = ((const float4*)beta)[c4];
        float4 r;
        r.x = (v.x - mean) * istd * ga.x + be.x; r.x = r.x >= 0.f ? r.x : NEG * r.x;
        r.y = (v.y - mean) * istd * ga.y + be.y; r.y = r.y >= 0.f ? r.y : NEG * r.y;
        r.z = (v.z - mean) * istd * ga.z + be.z; r.z = r.z >= 0.f ? r.z : NEG * r.z;
        r.w = (v.w - mean) * istd * ga.w + be.w; r.w = r.w >= 0.f ? r.w : NEG * r.w;
        ((float4*)out)[idx] = r;
    }
}

extern "C" void kernel_launch(void* const* d_in, const int* in_sizes, int n_in,
                              void* d_out, int out_size, void* d_ws, size_t ws_size,
                              hipStream_t stream) {
    const float* sfeats = (const float*)d_in[0];
    const float* qpts   = (const float*)d_in[1];
    const float* spts   = (const float*)d_in[2];
    const int*   nidx   = (const int*)  d_in[3];
    const float* kpts   = (const float*)d_in[4];
    const float* wts    = (const float*)d_in[5];
    const float* bias   = (const float*)d_in[6];
    const float* gamma  = (const float*)d_in[7];
    const float* beta   = (const float*)d_in[8];

    float* ws = (float*)d_ws;
    float*          rowsum = ws + OFF_ROWSUM;
    unsigned short* fb     = (unsigned short*)(ws + OFF_FB);
    unsigned short* wb     = (unsigned short*)(ws + OFF_WB);
    float*          ps     = ws + OFF_PS;
    float*          pq     = ws + OFF_PQ;
    float*          stat   = ws + OFF_STAT;
    float*          out    = (float*)d_out;

    k_prep <<<dim3((NSUP + 3) / 4), dim3(256), 0, stream>>>(sfeats, rowsum, fb);
    k_wpack<<<dim3(240),            dim3(256), 0, stream>>>(wts, wb);
    k_conv <<<dim3(NBLK),           dim3(256), 0, stream>>>(fb, qpts, spts, nidx, kpts,
                                                            wb, bias, rowsum, out, ps, pq);
    k_reduce<<<dim3(1),   dim3(1024), 0, stream>>>(ps, pq, stat);
    k_apply <<<dim3(1024), dim3(256), 0, stream>>>(out, stat, gamma, beta);
}

// Round 7
// 81.472 us; speedup vs baseline: 6.1978x; 1.0065x over previous
//
#include <hip/hip_runtime.h>
#include <hip/hip_bf16.h>
#include <math.h>

#define NSUP 50000
#define NQ   50000
#define NH   32
#define NK   15
#define NG   8
#define INV_SIGMA (1.0f/0.6f)
#define GN_EPS 1e-5f
#define NEG  0.1f

#define QB   16
#define NBLK (NQ/QB)       // 3125

// workspace layout (float offsets)
#define OFF_ROWSUM 0
#define OFF_FB     50048                       // ushort[50000*64]
#define OFF_WB     (OFF_FB + 1600000)          // ushort[61440] fragment-packed W
#define OFF_PS     (OFF_WB + 30720)
#define OFF_PQ     (OFF_PS + NBLK*8)
#define OFF_STAT   (OFF_PQ + NBLK*8)

typedef __attribute__((ext_vector_type(8))) short bf16x8;
typedef __attribute__((ext_vector_type(4))) float f32x4;
typedef __attribute__((ext_vector_type(4))) unsigned int u32x4;

__device__ __forceinline__ short f2bf(float x) {
    __hip_bfloat16 h = __float2bfloat16(x);
    return *reinterpret_cast<short*>(&h);
}

// ---------------- kernel 0: rowsum + fb convert (blocks < 12500), wpack (rest)
__global__ __launch_bounds__(256) void k_prep(const float* __restrict__ sf,
                                              float* __restrict__ rowsum,
                                              unsigned short* __restrict__ fb,
                                              const float* __restrict__ wts,
                                              unsigned short* __restrict__ wb) {
    if (blockIdx.x < 12500) {
        int row  = (blockIdx.x * 256 + threadIdx.x) >> 6;
        int lane = threadIdx.x & 63;
        if (row >= NSUP) return;
        float v = sf[(size_t)row * 64 + lane];
        fb[(size_t)row * 64 + lane] = (unsigned short)f2bf(v);
        float s = v;
        #pragma unroll
        for (int o = 32; o; o >>= 1) s += __shfl_down(s, o);
        if (lane == 0) rowsum[row] = s;
    } else {
        // pack W into B-fragment order (R2-exact):
        // [ks(30)][n(4)][lane(64)][j(8)] ; value = W[ks*32+(l>>4)*8+j][n*16+(l&15)]
        int idx = (blockIdx.x - 12500) * 256 + threadIdx.x;
        if (idx >= 30 * 4 * 64 * 8) return;
        int j  = idx & 7;
        int l  = (idx >> 3) & 63;
        int n  = (idx >> 9) & 3;
        int ks = idx >> 11;
        int r  = ks * 32 + ((l >> 4) << 3) + j;
        int d  = n * 16 + (l & 15);
        wb[idx] = (unsigned short)f2bf(wts[(size_t)r * 64 + d]);
    }
}

// ---------------- kernel 1: fused KPConv, both phases MFMA --------------------
__global__ __launch_bounds__(256, 5) void k_conv(
    const unsigned short* __restrict__ fb, const float* __restrict__ qpts,
    const float* __restrict__ spts,  const int*   __restrict__ nidx,
    const float* __restrict__ kpts,  const unsigned short* __restrict__ wb,
    const float* __restrict__ bias,  const float* __restrict__ rowsum,
    float* __restrict__ conv_out, float* __restrict__ part_s, float* __restrict__ part_q)
{
    // phase-2 A matrix [16 q][968] bf16 with 16B-chunk sigma swizzle
    //   sigma(ch) = ch ^ ((ch>>5)&3)  (involution; chunks<=119 stay < 121)
    // phase-1 alias: per wave 6144B region = F tile [32 h][144B], XOR chunks
    __shared__ __align__(16) short wl16[16 * 968];
    __shared__ __align__(16) float kp4[16][4];
    __shared__ float rcl[16];

    const int tid  = threadIdx.x;
    const int wv   = tid >> 6;
    const int lane = tid & 63;
    const int g    = lane >> 4;
    const int c16  = lane & 15;

    if (tid < 16) {
        if (tid < NK) {
            kp4[tid][0] = kpts[tid*3+0];
            kp4[tid][1] = kpts[tid*3+1];
            kp4[tid][2] = kpts[tid*3+2];
        } else {
            kp4[tid][0] = 1e8f; kp4[tid][1] = 1e8f; kp4[tid][2] = 1e8f;  // k=15 -> w=0
        }
        kp4[tid][3] = 0.f;
    }
    __syncthreads();

    const float kx = kp4[c16][0], ky = kp4[c16][1], kz = kp4[c16][2];

    const int qbase = blockIdx.x * QB;
    char* FP = (char*)wl16 + wv * 6144;    // [32 h][144B], XOR-swizzled chunks

    f32x4 pacc[4][4];
    #pragma unroll
    for (int a = 0; a < 4; a++)
        #pragma unroll
        for (int b = 0; b < 4; b++) pacc[a][b] = (f32x4){0.f,0.f,0.f,0.f};

    const int h    = lane & 31;
    const int half = lane >> 5;

    // ---- dxyz + valid-count for both query pairs, kept in registers --------
    float dxr[2], dyr[2], dzr[2];
    #pragma unroll
    for (int pp = 0; pp < 2; pp++) {
        const int qq = pp*2 + half;
        const int m  = qbase + wv*4 + qq;
        const float qx = qpts[m*3+0], qy = qpts[m*3+1], qz = qpts[m*3+2];
        const int  id  = nidx[(size_t)m * NH + h];
        const bool val = (id < NSUP);
        const int  ii  = val ? id : 0;
        const float dx = spts[ii*3+0]-qx, dy = spts[ii*3+1]-qy, dz = spts[ii*3+2]-qz;
        const float rs = rowsum[ii];
        unsigned long long bal = __ballot(val && rs > 0.f);
        int cA = __popcll(bal & 0xffffffffull); if (cA < 1) cA = 1;
        int cB = __popcll(bal >> 32);           if (cB < 1) cB = 1;
        if (lane == 0)  rcl[wv*4 + pp*2]     = 1.0f / (float)cA;
        if (lane == 32) rcl[wv*4 + pp*2 + 1] = 1.0f / (float)cB;
        dxr[pp] = val ? dx : 1e10f; dyr[pp] = dy; dzr[pp] = dz;
    }

    // ---- per-query loop, depth-1 gather pipeline ---------------------------
    const int gr = lane >> 3;     // row slot 0..7
    const int gs = lane & 7;      // 16B chunk 0..7
    int   idp[4];
    u32x4 vp[4];
    {
        const int m0 = qbase + wv*4;
        #pragma unroll
        for (int i = 0; i < 4; i++) idp[i] = nidx[(size_t)m0*NH + i*8 + gr];
        #pragma unroll
        for (int i = 0; i < 4; i++) {
            const int id2 = (idp[i] < NSUP) ? idp[i] : 0;
            vp[i] = *(const u32x4*)((const char*)fb + (size_t)id2*128 + gs*16);
        }
    }

    #pragma unroll
    for (int q = 0; q < 4; q++) {
        const int pp = q >> 1, e = q & 1;

        // write F tile (in-order DS: prior iter's reads already issued)
        #pragma unroll
        for (int i = 0; i < 4; i++)
            *(u32x4*)(FP + (i*8 + gr)*144 + ((gs ^ i) << 4)) = vp[i];

        // prefetch next query's nidx
        if (q < 3) {
            const int mn = qbase + wv*4 + q + 1;
            #pragma unroll
            for (int i = 0; i < 4; i++) idp[i] = nidx[(size_t)mn*NH + i*8 + gr];
        }

        // A-fragment via shuffles: w[h = g*8+j][k = c16], source lane e*32+h
        union { unsigned short u[8]; bf16x8 v; } ua;
        #pragma unroll
        for (int j = 0; j < 8; j++) {
            const int sl = e*32 + g*8 + j;
            const float px = __shfl(dxr[pp], sl);
            const float py = __shfl(dyr[pp], sl);
            const float pz = __shfl(dzr[pp], sl);
            const float ex = px - kx, ey = py - ky, ez = pz - kz;
            const float sq = fmaf(ex, ex, fmaf(ey, ey, ez * ez));
            const float w  = fmaxf(1.0f - sqrtf(sq) * INV_SIGMA, 0.f);
            ua.u[j] = (unsigned short)f2bf(w);
        }

        // prefetch next query's fb rows (latency hides under reads+MFMA+next w)
        if (q < 3) {
            #pragma unroll
            for (int i = 0; i < 4; i++) {
                const int id2 = (idp[i] < NSUP) ? idp[i] : 0;
                vp[i] = *(const u32x4*)((const char*)fb + (size_t)id2*128 + gs*16);
            }
        }

        // B-fragments (8x u16, 2-way banks) + MFMA
        #pragma unroll
        for (int ct = 0; ct < 4; ct++) {
            const char* vb = FP + (g*8)*144
                           + (((((ct << 1) | (c16 >> 3)) ^ g) & 7) << 4)
                           + ((c16 & 7) << 1);
            union { unsigned short u[8]; bf16x8 v; } ub;
            #pragma unroll
            for (int j = 0; j < 8; j++)
                ub.u[j] = *(const unsigned short*)(vb + j*144);
            pacc[q][ct] = __builtin_amdgcn_mfma_f32_16x16x32_bf16(ua.v, ub.v, pacc[q][ct], 0, 0, 0);
        }
    }

    __syncthreads();     // phase-1 LDS dead; wl16 becomes the phase-2 A matrix

    // ---- write A matrix: semantic chunk ch = kk*8+ct*2+hi at location sigma(ch)
    #pragma unroll
    for (int qq = 0; qq < 4; qq++) {
        #pragma unroll
        for (int ct = 0; ct < 4; ct++) {
            #pragma unroll
            for (int i = 0; i < 4; i++) {
                const int kk = g*4 + i;
                if (kk < NK) {
                    const int ch = kk*8 + ct*2 + (c16 >> 3);
                    const int sc = ch ^ ((ch >> 5) & 3);
                    wl16[(wv*4 + qq)*968 + sc*8 + (c16 & 7)] = f2bf(pacc[qq][ct][i]);
                }
            }
        }
    }
    __syncthreads();

    // ---------------- phase 2: 16x960 @ 960x64 via MFMA (sigma on A-read) ----
    f32x4 facc = (f32x4){0.f,0.f,0.f,0.f};
    const int z = lane >> 4;
    const short* arow = wl16 + c16*968;
    const unsigned short* bp = wb + ((size_t)(wv * 64 + lane)) * 8;
    #pragma unroll 6
    for (int ks = 0; ks < 30; ks++) {
        const int L  = ks*4 + z;
        const int sL = L ^ ((L >> 5) & 3);
        bf16x8 a = *(const bf16x8*)(arow + sL*8);
        bf16x8 b = *(const bf16x8*)(bp + (size_t)ks*2048);
        facc = __builtin_amdgcn_mfma_f32_16x16x32_bf16(a, b, facc, 0, 0, 0);
    }

    // ---------------- epilogue: /nbr_num + bias, GN partials (R2-exact) ------
    const int   d  = wv*16 + c16;
    const float bs = bias[d];
    float gl = 0.f, gq = 0.f;
    #pragma unroll
    for (int i = 0; i < 4; i++) {
        const int row = z*4 + i;
        const float y = facc[i] * rcl[row] + bs;
        conv_out[(size_t)(qbase + row)*64 + d] = y;
        gl += y;
        gq = fmaf(y, y, gq);
    }
    #pragma unroll
    for (int msk = 1; msk <= 4; msk <<= 1) { gl += __shfl_xor(gl, msk); gq += __shfl_xor(gq, msk); }
    gl += __shfl_xor(gl, 16); gq += __shfl_xor(gq, 16);
    gl += __shfl_xor(gl, 32); gq += __shfl_xor(gq, 32);
    if ((lane & 55) == 0) {
        const int grp = wv*2 + (lane >> 3);
        part_s[(size_t)blockIdx.x * 8 + grp] = gl;
        part_q[(size_t)blockIdx.x * 8 + grp] = gq;
    }
}

// ---------------- kernel 2: deterministic stats reduction ---------------------
__global__ __launch_bounds__(1024) void k_reduce(const float* __restrict__ part_s,
                                                 const float* __restrict__ part_q,
                                                 float* __restrict__ stat) {
    __shared__ double ds[128][8], dq[128][8];
    const int t = threadIdx.x;
    const int g = t & 7, chunk = t >> 3;
    const int per = (NBLK + 127) / 128;
    double s = 0.0, q = 0.0;
    int lo = chunk * per, hi = lo + per; if (hi > NBLK) hi = NBLK;
    for (int i = lo; i < hi; i++) {
        s += (double)part_s[(size_t)i * 8 + g];
        q += (double)part_q[(size_t)i * 8 + g];
    }
    ds[chunk][g] = s; dq[chunk][g] = q;
    __syncthreads();
    if (t < 8) {
        double S = 0.0, Q = 0.0;
        for (int cix = 0; cix < 128; cix++) { S += ds[cix][t]; Q += dq[cix][t]; }
        const double cnt = (double)(64 / NG) * (double)NQ;
        double mean = S / cnt;
        double var  = Q / cnt - mean * mean;
        stat[t]     = (float)mean;
        stat[8 + t] = (float)(1.0 / sqrt(var + (double)GN_EPS));
    }
}

// ---------------- kernel 3: normalize + affine + LeakyReLU (in-place) ---------
__global__ __launch_bounds__(256) void k_apply(float* __restrict__ out,
                                               const float* __restrict__ stat,
                                               const float* __restrict__ gamma,
                                               const float* __restrict__ beta) {
    const int n4 = NQ * 64 / 4;
    for (int idx = blockIdx.x * 256 + threadIdx.x; idx < n4; idx += gridDim.x * 256) {
        float4 v = ((const float4*)out)[idx];
        const int c4 = idx & 15;
        const int g  = c4 >> 1;
        const float mean = stat[g], istd = stat[8 + g];
        const float4 ga = ((const float4*)gamma)[c4];
        const float4 be = ((const float4*)beta)[c4];
        float4 r;
        r.x = (v.x - mean) * istd * ga.x + be.x; r.x = r.x >= 0.f ? r.x : NEG * r.x;
        r.y = (v.y - mean) * istd * ga.y + be.y; r.y = r.y >= 0.f ? r.y : NEG * r.y;
        r.z = (v.z - mean) * istd * ga.z + be.z; r.z = r.z >= 0.f ? r.z : NEG * r.z;
        r.w = (v.w - mean) * istd * ga.w + be.w; r.w = r.w >= 0.f ? r.w : NEG * r.w;
        ((float4*)out)[idx] = r;
    }
}

extern "C" void kernel_launch(void* const* d_in, const int* in_sizes, int n_in,
                              void* d_out, int out_size, void* d_ws, size_t ws_size,
                              hipStream_t stream) {
    const float* sfeats = (const float*)d_in[0];
    const float* qpts   = (const float*)d_in[1];
    const float* spts   = (const float*)d_in[2];
    const int*   nidx   = (const int*)  d_in[3];
    const float* kpts   = (const float*)d_in[4];
    const float* wts    = (const float*)d_in[5];
    const float* bias   = (const float*)d_in[6];
    const float* gamma  = (const float*)d_in[7];
    const float* beta   = (const float*)d_in[8];

    float* ws = (float*)d_ws;
    float*          rowsum = ws + OFF_ROWSUM;
    unsigned short* fb     = (unsigned short*)(ws + OFF_FB);
    unsigned short* wb     = (unsigned short*)(ws + OFF_WB);
    float*          ps     = ws + OFF_PS;
    float*          pq     = ws + OFF_PQ;
    float*          stat   = ws + OFF_STAT;
    float*          out    = (float*)d_out;

    k_prep <<<dim3(12740), dim3(256), 0, stream>>>(sfeats, rowsum, fb, wts, wb);
    k_conv <<<dim3(NBLK),  dim3(256), 0, stream>>>(fb, qpts, spts, nidx, kpts,
                                                   wb, bias, rowsum, out, ps, pq);
    k_reduce<<<dim3(1),    dim3(1024), 0, stream>>>(ps, pq, stat);
    k_apply <<<dim3(1024), dim3(256), 0, stream>>>(out, stat, gamma, beta);
}